// Round 9
// baseline (2816.125 us; speedup 1.0000x reference)
//
#include <hip/hip_runtime.h>
#include <hip/hip_bf16.h>
#include <stdint.h>

// SimpleRNN: B=64, S=512, H=1024, V=128
// Phase 1 (R23 = R22 resubmit; container failed, no signal): TWO-STREAM
//   SOFTWARE PIPELINE over the R15-proven protocol.
//   Evidence: R14==R15==3.0us/step with 2x different per-wg work => step time
//   is pure inter-step latency (publish->propagate->detect->load legs), and
//   all 6 attempts to shrink the legs (R16-R21) were neutral or worse.
//   So: hide the legs under an INDEPENDENT recurrence. 32 wgs (one per
//   32-col group) each alternate stream A (batch rows 0-31) and stream B
//   (rows 32-63). While A's step-s publication propagates through L3, the wg
//   computes B's step-s; A(s+1) data has landed when we next poll it.
//   Per-stream protocol is R15 VERBATIM: per-wave flags, h store -> per-wave
//   vmcnt(0) -> flag, lane-parallel 32-flag poll, triple-gen h buffers in
//   MFMA A-frag layout, descending-vmcnt load pipeline, __syncthreads
//   reduction barriers, shared ldsW + red.
// Phase 2: logits GEMM (hidden bf16 @ W_out bf16, 32x32x16 MFMA) + b_out
//   (unchanged; g_hidden layout identical).

#define Bz 64
#define Sz 512
#define Hz 1024
#define Vz 128
#define NWG 32    // one wg per 32-col group; each runs 2 batch streams
#define COLS 32   // columns of W_hh per workgroup
#define WGT 512   // 8 waves = 8-way K-split (128 k each)

typedef __attribute__((ext_vector_type(8)))  short short8;
typedef __attribute__((ext_vector_type(16))) float f32x16;
typedef __attribute__((ext_vector_type(4)))  unsigned u32x4;   // asm-friendly 16B

// h TRIPLE buffer in MFMA A-fragment order:
// g_hfrag[gen][bh][kb=k>>4][lane=((k>>3)&1)*32+r][j=k&7], r = row within half
__device__ __align__(16) unsigned short g_hfrag[3][2][64][64][8];   // 3 x 128 KB
// hidden states, fragment order per step: [s][bh][kb][lane][8]  (64 MB)
__device__ __align__(16) unsigned short g_hidden[(size_t)Sz*2*64*64*8];
// W_out packed for 32x32x16 B-frags: [kb][nt][lane][8]  (256 KB)
__device__ __align__(16) unsigned short g_wout[64*4*64*8];

__device__ __forceinline__ unsigned short f2bf(float f) {
  union { float f; unsigned u; } v; v.f = f;
  unsigned r = v.u + 0x7FFFu + ((v.u >> 16) & 1u);      // RNE
  return (unsigned short)(r >> 16);
}

__device__ __forceinline__ float fast_tanh(float x) {
  float cx = fminf(9.0f, fmaxf(-9.0f, x));
  float e  = __builtin_amdgcn_exp2f(cx * 2.88539008178f);   // e^(2x)
  return (e - 1.0f) * __builtin_amdgcn_rcpf(e + 1.0f);
}

// 8 coherent (sc1 -> L3) 16-B loads, NO drain — pipeline issue stage.
// Each instruction is a fully-coalesced 1 KB wave read (lane stride 16 B).
__device__ __forceinline__ void load8_nodrain(const unsigned short* p0, u32x4 t[8]) {
  const unsigned short* p1 = p0 + 2048;   // +4096 B (4 planes)
  asm volatile(
    "global_load_dwordx4 %0, %8, off sc1\n\t"
    "global_load_dwordx4 %1, %8, off offset:1024 sc1\n\t"
    "global_load_dwordx4 %2, %8, off offset:2048 sc1\n\t"
    "global_load_dwordx4 %3, %8, off offset:3072 sc1\n\t"
    "global_load_dwordx4 %4, %9, off sc1\n\t"
    "global_load_dwordx4 %5, %9, off offset:1024 sc1\n\t"
    "global_load_dwordx4 %6, %9, off offset:2048 sc1\n\t"
    "global_load_dwordx4 %7, %9, off offset:3072 sc1"
    : "=&v"(t[0]), "=&v"(t[1]), "=&v"(t[2]), "=&v"(t[3]),
      "=&v"(t[4]), "=&v"(t[5]), "=&v"(t[6]), "=&v"(t[7])
    : "v"(p0), "v"(p1)
    : "memory");
}

// agent-scope write-through stores (visible at L3 once vmcnt retires)
__device__ __forceinline__ void store16_sc1(unsigned short* p, u32x4 v) {
  asm volatile("global_store_dwordx4 %0, %1, off sc1" :: "v"(p), "v"(v) : "memory");
}
__device__ __forceinline__ void store4_sc1(unsigned short* p, unsigned v) {
  asm volatile("global_store_dword %0, %1, off sc1" :: "v"(p), "v"(v) : "memory");
}

// ---- Phase 0: pack W_out (H,V) fp32 -> [kb][nt][lane][8] bf16 (32x32 B-frag) --
__global__ void pack_wout(const float* __restrict__ W_out) {
  int gid = blockIdx.x * blockDim.x + threadIdx.x;      // 0..16383
  int lane = gid & 63;
  int nt   = (gid >> 6) & 3;
  int kb   = gid >> 8;
  int n = nt * 32 + (lane & 31);
  int k0 = kb * 16 + (lane >> 5) * 8;
  unsigned short t[8];
#pragma unroll
  for (int j = 0; j < 8; ++j)
    t[j] = f2bf(W_out[(size_t)(k0 + j) * Vz + n]);
  uint4 w;
  w.x = (unsigned)t[0] | ((unsigned)t[1] << 16);
  w.y = (unsigned)t[2] | ((unsigned)t[3] << 16);
  w.z = (unsigned)t[4] | ((unsigned)t[5] << 16);
  w.w = (unsigned)t[6] | ((unsigned)t[7] << 16);
  *(uint4*)&g_wout[(size_t)gid * 8] = w;
}

// ---------------- Phase 1: persistent recurrence -----------------------------
__global__ __launch_bounds__(WGT) void rnn_persistent(
    const int* __restrict__ x, const float* __restrict__ h0,
    const float* __restrict__ W_xh, const float* __restrict__ W_hh,
    const float* __restrict__ b_h, float* __restrict__ out,
    unsigned* __restrict__ flags)
{
  // W slice (32 cols): [kb(64)][lane=kq*32+n][8] -> B-frag via ds_read_b128
  __shared__ unsigned short ldsW[64 * 64 * 8];          // 64 KB
  // 8 K-split partial regions, XOR-swizzled: red[ki*1024 + m*32 + (c^m)]
  // (serially shared by the two streams)
  __shared__ float red[8 * 1024];                       // 32 KB
  // 96 KB total -> 1 wg per CU

  const int g    = blockIdx.x;        // 0..31 = col-group
  const int n0g  = g * COLS;          // global column base of W slice
  const int tid  = threadIdx.x;
  const int lane = tid & 63;
  const int ki   = tid >> 6;          // wave = K-split 0..7 (128 k each)
  const int bn   = lane & 31;

  // ---- stage W_hh[:, n0g : n0g+32) -> ldsW (one-time) ----
  for (int idx = tid; idx < 64 * 64; idx += WGT) {
    int kb = idx >> 6, L = idx & 63;
    int n = L & 31, kq = L >> 5;
    unsigned short t[8];
#pragma unroll
    for (int j = 0; j < 8; ++j)
      t[j] = f2bf(W_hh[(size_t)(kb * 16 + kq * 8 + j) * Hz + n0g + n]);
    uint4 w;
    w.x = (unsigned)t[0] | ((unsigned)t[1] << 16);
    w.y = (unsigned)t[2] | ((unsigned)t[3] << 16);
    w.z = (unsigned)t[4] | ((unsigned)t[5] << 16);
    w.w = (unsigned)t[6] | ((unsigned)t[7] << 16);
    *(uint4*)&ldsW[(size_t)idx * 8] = w;
  }

  // ---- h0 -> g_hfrag[0] (both halves); wg g stages lines [g*256, +256) ----
  if (tid < 256) {
    int s_idx = g * 256 + tid;              // 0..8191 over all wgs
    int fbh = s_idx >> 12, fkb = (s_idx >> 6) & 63, fL = s_idx & 63;
    int m = fbh * 32 + (fL & 31);
    int k = fkb * 16 + (fL >> 5) * 8;
    const float* src = &h0[(size_t)m * Hz + k];
    float4 a0 = *(const float4*)&src[0];
    float4 a1 = *(const float4*)&src[4];
    u32x4 w;
    w.x = (unsigned)f2bf(a0.x) | ((unsigned)f2bf(a0.y) << 16);
    w.y = (unsigned)f2bf(a0.z) | ((unsigned)f2bf(a0.w) << 16);
    w.z = (unsigned)f2bf(a1.x) | ((unsigned)f2bf(a1.y) << 16);
    w.w = (unsigned)f2bf(a1.z) | ((unsigned)f2bf(a1.w) << 16);
    store16_sc1(&g_hfrag[0][fbh][fkb][fL][0], w);
  }

  // ---- init: LDS ready; each wave certifies its OWN stores, posts both ----
  __syncthreads();                                  // ldsW visible to all waves
  asm volatile("s_waitcnt vmcnt(0)" ::: "memory");  // per-wave h0-store drain
  if (lane == 0) {
    __hip_atomic_store(&flags[((0 * 32 + g) * 8 + ki) * 4], 1u,
                       __ATOMIC_RELAXED, __HIP_MEMORY_SCOPE_AGENT);
    __hip_atomic_store(&flags[((1 * 32 + g) * 8 + ki) * 4], 1u,
                       __ATOMIC_RELAXED, __HIP_MEMORY_SCOPE_AGENT);
  }

  // epilogue mapping: 512 threads -> 32 rows x 16 col-pairs (per stream)
  const int er   = tid & 31;                  // row within batch half
  const int c0   = (tid >> 5) * 2;            // col within wg slice (even)
  const int kcol = n0g + c0;                  // global h column
  const int kb_g = kcol >> 4;
  const int kq2  = (kcol >> 3) & 1;
  const int lslot = kq2 * 32 + er;
  const float bias0 = b_h[kcol], bias1 = b_h[kcol + 1];

  // prefetch step-0 tokens + embedding pairs for both streams
  const int emA = 0 * 32 + er, emB = 1 * 32 + er;
  float2 xvA_n = *(const float2*)&W_xh[(size_t)x[emA * Sz] * Hz + kcol];
  float2 xvB_n = *(const float2*)&W_xh[(size_t)x[emB * Sz] * Hz + kcol];

  // one full stream-step (R15-proven sequence), parameterized by batch half
  auto stream_step = [&](int sbh, float2& xvn, int s, int rp, int wp) {
    const unsigned tgt = (unsigned)(s + 1);   // producers' step-s data flag
    const int em = sbh * 32 + er;

    // fine-grained parallel WAIT on 32 producer WAVES (R15-proven mapping)
    {
      const int pflag =
          ((sbh * 32 + ki * 4 + (lane >> 3)) * 8 + (lane & 7)) * 4;
      for (int it = 0; it < 65536; ++it) {
        unsigned v = 0xFFFFFFFFu;
        if (lane < 32)
          v = __hip_atomic_load(&flags[pflag], __ATOMIC_RELAXED,
                                __HIP_MEMORY_SCOPE_AGENT);
        if (__all(v >= tgt)) break;
        __builtin_amdgcn_s_sleep(1);
      }
      asm volatile("" ::: "memory");
    }

    // issue all 8 A-fragment loads (no drain), consume pairwise with
    // descending vmcnt gates (poll drained vmem -> clean slate at issue).
    u32x4 t[8];
    load8_nodrain(&g_hfrag[rp][sbh][ki * 8][lane][0], t);
    f32x16 acc0 = {}, acc1 = {};

#define STAGE(J, CNT)                                                          \
    {                                                                          \
      asm volatile("s_waitcnt vmcnt(" #CNT ")"                                 \
                   : "+v"(t[2 * (J)]), "+v"(t[2 * (J) + 1]));                  \
      const int kbp = ki * 8 + 2 * (J);                                        \
      short8 ba = *(const short8*)&ldsW[(size_t)(kbp * 64 + lane) * 8];        \
      short8 bb = *(const short8*)&ldsW[(size_t)((kbp + 1) * 64 + lane) * 8];  \
      acc0 = __builtin_amdgcn_mfma_f32_32x32x16_bf16(*(short8*)&t[2 * (J)],    \
                                                     ba, acc0, 0, 0, 0);       \
      acc1 = __builtin_amdgcn_mfma_f32_32x32x16_bf16(*(short8*)&t[2 * (J) + 1],\
                                                     bb, acc1, 0, 0, 0);       \
    }
    STAGE(0, 6) STAGE(1, 4) STAGE(2, 2) STAGE(3, 0)
#undef STAGE

    // prefetch NEXT step's token + embedding pair for this stream
    float2 xv = xvn;
    if (s + 1 < Sz) {
      int t2 = x[em * Sz + s + 1];
      xvn = *(const float2*)&W_xh[(size_t)t2 * Hz + kcol];
    }

    __syncthreads();   // BAR-A: other stream's epilogue done reading red
    // C/D: col=lane&31, row=(reg&3)+8*(reg>>2)+4*(lane>>5)  [m74/m101]
    {
#pragma unroll
      for (int r = 0; r < 16; ++r) {
        int m = 4 * (lane >> 5) + (r & 3) + 8 * (r >> 2);
        red[ki * 1024 + m * 32 + (bn ^ m)] = acc0[r] + acc1[r];
      }
    }
    __syncthreads();   // BAR-B: all 8 partials in red

    // epilogue: z = sum of 8 partials + emb + bias; h = tanh(z)
    float z0, z1;
    {
      const int o0 = er * 32 + (c0 ^ er);
      const int o1 = er * 32 + ((c0 + 1) ^ er);
      z0 = ((red[o0] + red[1024 + o0]) + (red[2048 + o0] + red[3072 + o0])) +
           ((red[4096 + o0] + red[5120 + o0]) + (red[6144 + o0] + red[7168 + o0]));
      z1 = ((red[o1] + red[1024 + o1]) + (red[2048 + o1] + red[3072 + o1])) +
           ((red[4096 + o1] + red[5120 + o1]) + (red[6144 + o1] + red[7168 + o1]));
    }
    z0 = fast_tanh(z0 + xv.x + bias0);
    z1 = fast_tanh(z1 + xv.y + bias1);

    unsigned w2 = (unsigned)f2bf(z0) | ((unsigned)f2bf(z1) << 16);

    // h store -> per-wave drain -> per-wave flag publish (R15-proven)
    const size_t slotOff =
        (((size_t)sbh * 64 + kb_g) * 64 + lslot) * 8 + (kcol & 7);
    store4_sc1(&((unsigned short*)g_hfrag)[(size_t)wp * 65536 + slotOff], w2);
    asm volatile("s_waitcnt vmcnt(0)" ::: "memory");   // own stores visible
    if (lane == 0)
      __hip_atomic_store(&flags[((sbh * 32 + g) * 8 + ki) * 4],
                         (unsigned)(s + 2), __ATOMIC_RELAXED,
                         __HIP_MEMORY_SCOPE_AGENT);

    // off the publish path:
    *(unsigned*)&g_hidden[(size_t)s * 65536 + slotOff] = w2;
    if (s == Sz - 1) {
      float* hf = out + (size_t)Bz * Sz * Vz + (size_t)em * Hz + kcol;
      hf[0] = z0; hf[1] = z1;
    }
  };

  int rp = 0;                               // read generation = s % 3
  for (int s = 0; s < Sz; ++s) {
    const int wp = (rp == 2) ? 0 : rp + 1;  // write generation
    stream_step(0, xvA_n, s, rp, wp);       // stream A: rows 0-31
    stream_step(1, xvB_n, s, rp, wp);       // stream B: rows 32-63 (hides A's legs)
    rp = wp;
  }
}

// ---------------- Phase 2: logits = hidden @ W_out + b_out -------------------
// grid: 1024 blocks = (s, mi); 4 waves; wave nt computes 32 rows x 32 cols, K=1024
__global__ __launch_bounds__(256) void logits_gemm(
    const float* __restrict__ b_out, float* __restrict__ out)
{
  const int tid = threadIdx.x, lane = tid & 63, nt = tid >> 6;
  const int s = blockIdx.x >> 1, mi = blockIdx.x & 1;
  const unsigned short* ab = &g_hidden[((size_t)s * 8192 + (size_t)mi * 4096) * 8];

  f32x16 acc = {};
#pragma unroll 8
  for (int kb = 0; kb < 64; ++kb) {
    short8 a = *(const short8*)&ab[(size_t)(kb * 64 + lane) * 8];
    short8 b = *(const short8*)&g_wout[(size_t)((kb * 4 + nt) * 64 + lane) * 8];
    acc = __builtin_amdgcn_mfma_f32_32x32x16_bf16(a, b, acc, 0, 0, 0);
  }
  const int col = nt * 32 + (lane & 31);
  const float bo = b_out[col];
  const int rbase = 4 * (lane >> 5);
#pragma unroll
  for (int r = 0; r < 16; ++r) {
    int m = rbase + (r & 3) + 8 * (r >> 2);
    int em = mi * 32 + m;
    out[((size_t)em * Sz + s) * Vz + col] = acc[r] + bo;
  }
}

// ---------------- host launcher ----------------------------------------------
extern "C" void kernel_launch(void* const* d_in, const int* in_sizes, int n_in,
                              void* d_out, int out_size, void* d_ws, size_t ws_size,
                              hipStream_t stream) {
  const int*   x     = (const int*)d_in[0];
  const float* h0    = (const float*)d_in[1];
  const float* W_xh  = (const float*)d_in[2];
  const float* W_hh  = (const float*)d_in[3];
  const float* b_h   = (const float*)d_in[4];
  const float* W_out = (const float*)d_in[5];
  const float* b_out = (const float*)d_in[6];
  float* out = (float*)d_out;

  (void)hipMemsetAsync(d_ws, 0, 8192, stream);    // 512 wave-flag slots (16 B)
  pack_wout<<<64, 256, 0, stream>>>(W_out);
  rnn_persistent<<<NWG, WGT, 0, stream>>>(x, h0, W_xh, W_hh, b_h, out,
                                          (unsigned*)d_ws);
  logits_gemm<<<Sz * 2, 256, 0, stream>>>(b_out, out);
}

// Round 10
// 1803.404 us; speedup vs baseline: 1.5616x; 1.5616x over previous
//
#include <hip/hip_runtime.h>
#include <hip/hip_bf16.h>
#include <stdint.h>

// SimpleRNN: B=64, S=512, H=1024, V=128
// Phase 1 (R24): HALVED READ BURST, R15 pipeline intact.
//   Theory: R13/R14/R15 all == 3.0us/step; leg-by-leg RTT math accounts for
//   ~1.8us; the residual tracks the synchronized 4 MB/step L3 read burst.
//   R20's burst-halving test was confounded (LDS staging conflicts, 16 CUs).
//   Clean test: 32 wgs = 2 batch-halves x 16 col-groups of 64 cols. W_hh
//   slice in VGPRs (16 B-frags = 64 VGPR/thread; packing formula correctness-
//   proven in R20). A-frag load path, exchange buffers, flag protocol are
//   R15-VERBATIM (load8_nodrain + descending vmcnt, per-wave flags,
//   store->vmcnt(0)->flag, triple-gen h). Read burst: 32 x 64 KB = 2 MB/step
//   (was 4). No h staging through LDS (R20's conflict path eliminated);
//   LDS = 64 KB reduce (XOR-swizzled, <=2 lanes/bank both sides) + pad ->
//   96 KB forces 1 wg/CU.
// Phase 2: logits GEMM (hidden bf16 @ W_out bf16, 32x32x16 MFMA) + b_out
//   (unchanged; g_hidden layout identical).

#define Bz 64
#define Sz 512
#define Hz 1024
#define Vz 128
#define NWG 32    // 2 batch-halves x 16 col-groups
#define COLS 64   // columns of W_hh per workgroup
#define WGT 512   // 8 waves = 8-way K-split (128 k each)

typedef __attribute__((ext_vector_type(8)))  short short8;
typedef __attribute__((ext_vector_type(16))) float f32x16;
typedef __attribute__((ext_vector_type(4)))  unsigned u32x4;   // asm-friendly 16B
typedef __attribute__((ext_vector_type(2)))  unsigned u32x2;   // asm-friendly 8B

// h TRIPLE buffer in MFMA A-fragment order:
// g_hfrag[gen][bh][kb=k>>4][slot=((k>>3)&1)*32+r][j=k&7], r = row within half
__device__ __align__(16) unsigned short g_hfrag[3][2][64][64][8];   // 3 x 128 KB
// hidden states, fragment order per step: [s][bh][kb][slot][8]  (64 MB)
__device__ __align__(16) unsigned short g_hidden[(size_t)Sz*2*64*64*8];
// W_out packed for 32x32x16 B-frags: [kb][nt][lane][8]  (256 KB)
__device__ __align__(16) unsigned short g_wout[64*4*64*8];

__device__ __forceinline__ unsigned short f2bf(float f) {
  union { float f; unsigned u; } v; v.f = f;
  unsigned r = v.u + 0x7FFFu + ((v.u >> 16) & 1u);      // RNE
  return (unsigned short)(r >> 16);
}

__device__ __forceinline__ float fast_tanh(float x) {
  float cx = fminf(9.0f, fmaxf(-9.0f, x));
  float e  = __builtin_amdgcn_exp2f(cx * 2.88539008178f);   // e^(2x)
  return (e - 1.0f) * __builtin_amdgcn_rcpf(e + 1.0f);
}

// 8 coherent (sc1 -> L3) 16-B loads, NO drain — pipeline issue stage.
// Each instruction is a fully-coalesced 1 KB wave read (lane stride 16 B).
__device__ __forceinline__ void load8_nodrain(const unsigned short* p0, u32x4 t[8]) {
  const unsigned short* p1 = p0 + 2048;   // +4096 B (4 planes)
  asm volatile(
    "global_load_dwordx4 %0, %8, off sc1\n\t"
    "global_load_dwordx4 %1, %8, off offset:1024 sc1\n\t"
    "global_load_dwordx4 %2, %8, off offset:2048 sc1\n\t"
    "global_load_dwordx4 %3, %8, off offset:3072 sc1\n\t"
    "global_load_dwordx4 %4, %9, off sc1\n\t"
    "global_load_dwordx4 %5, %9, off offset:1024 sc1\n\t"
    "global_load_dwordx4 %6, %9, off offset:2048 sc1\n\t"
    "global_load_dwordx4 %7, %9, off offset:3072 sc1"
    : "=&v"(t[0]), "=&v"(t[1]), "=&v"(t[2]), "=&v"(t[3]),
      "=&v"(t[4]), "=&v"(t[5]), "=&v"(t[6]), "=&v"(t[7])
    : "v"(p0), "v"(p1)
    : "memory");
}

// agent-scope write-through stores (visible at L3 once vmcnt retires)
__device__ __forceinline__ void store16_sc1(unsigned short* p, u32x4 v) {
  asm volatile("global_store_dwordx4 %0, %1, off sc1" :: "v"(p), "v"(v) : "memory");
}
__device__ __forceinline__ void store8_sc1(unsigned short* p, u32x2 v) {
  asm volatile("global_store_dwordx2 %0, %1, off sc1" :: "v"(p), "v"(v) : "memory");
}

// ---- Phase 0: pack W_out (H,V) fp32 -> [kb][nt][lane][8] bf16 (32x32 B-frag) --
__global__ void pack_wout(const float* __restrict__ W_out) {
  int gid = blockIdx.x * blockDim.x + threadIdx.x;      // 0..16383
  int lane = gid & 63;
  int nt   = (gid >> 6) & 3;
  int kb   = gid >> 8;
  int n = nt * 32 + (lane & 31);
  int k0 = kb * 16 + (lane >> 5) * 8;
  unsigned short t[8];
#pragma unroll
  for (int j = 0; j < 8; ++j)
    t[j] = f2bf(W_out[(size_t)(k0 + j) * Vz + n]);
  uint4 w;
  w.x = (unsigned)t[0] | ((unsigned)t[1] << 16);
  w.y = (unsigned)t[2] | ((unsigned)t[3] << 16);
  w.z = (unsigned)t[4] | ((unsigned)t[5] << 16);
  w.w = (unsigned)t[6] | ((unsigned)t[7] << 16);
  *(uint4*)&g_wout[(size_t)gid * 8] = w;
}

// ---------------- Phase 1: persistent recurrence -----------------------------
__global__ __launch_bounds__(WGT) void rnn_persistent(
    const int* __restrict__ x, const float* __restrict__ h0,
    const float* __restrict__ W_xh, const float* __restrict__ W_hh,
    const float* __restrict__ b_h, float* __restrict__ out,
    unsigned* __restrict__ flags)
{
  // 8 K-split partial regions (32 rows x 64 cols each), XOR-swizzled:
  // red[ki*2048 + m*64 + (c ^ m)], m=row 0..31, c=col 0..63.
  // Padded to 96 KB to force 1 wg/CU (spread across 32 CUs).
  __shared__ float red[24576];

  const int g    = blockIdx.x;        // 0..31
  const int bh   = g >> 4;            // batch half (rows bh*32 .. +32)
  const int cg   = g & 15;            // col-group
  const int n0g  = cg * COLS;         // global column base of W slice
  const int tid  = threadIdx.x;
  const int lane = tid & 63;
  const int ki   = tid >> 6;          // wave = K-split 0..7 (128 k each)

  // ---- W_hh B-frags -> VGPRs (one-time; packing formula proven in R20) ----
  // wf[nt][p]: k = ki*128 + p*16 + (lane>>5)*8 + j ; col = n0g+nt*32+(lane&31)
  short8 wf[2][8];
  {
#pragma unroll
    for (int nt = 0; nt < 2; ++nt) {
      const int col = n0g + nt * 32 + (lane & 31);
      const float* wb = &W_hh[(size_t)(ki * 128 + (lane >> 5) * 8) * Hz + col];
#pragma unroll
      for (int p = 0; p < 8; ++p) {
        const float* wp_ = wb + (size_t)p * 16 * Hz;
        unsigned short tt[8];
#pragma unroll
        for (int j = 0; j < 8; ++j) tt[j] = f2bf(wp_[(size_t)j * Hz]);
        short8 w;
        w[0]=(short)tt[0]; w[1]=(short)tt[1]; w[2]=(short)tt[2]; w[3]=(short)tt[3];
        w[4]=(short)tt[4]; w[5]=(short)tt[5]; w[6]=(short)tt[6]; w[7]=(short)tt[7];
        wf[nt][p] = w;
      }
    }
  }

  // ---- h0 -> g_hfrag[0]; wg g stages lines [g*256, g*256+256) of 8192 ----
  if (tid < 256) {
    int s_idx = g * 256 + tid;
    int fbh = s_idx >> 12, fkb = (s_idx >> 6) & 63, fL = s_idx & 63;
    int m = fbh * 32 + (fL & 31);
    int k = fkb * 16 + (fL >> 5) * 8;
    const float* src = &h0[(size_t)m * Hz + k];
    float4 a0 = *(const float4*)&src[0];
    float4 a1 = *(const float4*)&src[4];
    u32x4 w;
    w.x = (unsigned)f2bf(a0.x) | ((unsigned)f2bf(a0.y) << 16);
    w.y = (unsigned)f2bf(a0.z) | ((unsigned)f2bf(a0.w) << 16);
    w.z = (unsigned)f2bf(a1.x) | ((unsigned)f2bf(a1.y) << 16);
    w.w = (unsigned)f2bf(a1.z) | ((unsigned)f2bf(a1.w) << 16);
    store16_sc1(&g_hfrag[0][fbh][fkb][fL][0], w);
  }

  // ---- init publish: each wave certifies its OWN stores (per-wave vmcnt) ----
  asm volatile("s_waitcnt vmcnt(0)" ::: "memory");
  if (lane == 0)
    __hip_atomic_store(&flags[(g * 8 + ki) * 4], 1u, __ATOMIC_RELAXED,
                       __HIP_MEMORY_SCOPE_AGENT);

  // epilogue mapping: 512 threads -> 32 rows x 16 col-quads
  const int er   = tid & 31;                  // row within batch half
  const int em   = bh * 32 + er;              // global batch row
  const int jc   = tid >> 5;                  // col-quad 0..15 (= 2*ki + lane>>5)
  const int c0   = jc * 4;                    // col within wg slice
  const int kcol = n0g + c0;                  // global h column
  const int kb_g = kcol >> 4;
  const int kq2  = (kcol >> 3) & 1;
  const int lslot = kq2 * 32 + er;
  const size_t slotOff =
      (((size_t)bh * 64 + kb_g) * 64 + lslot) * 8 + (kcol & 7);
  float4 bias = *(const float4*)&b_h[kcol];

  // consumer watch list: 16 producer-wave flags (2 producer wgs x 8 waves);
  // k-slice [ki*128,+128) <-> producer col-groups {2ki, 2ki+1} of this bh.
  const int pflag =
      ((bh * 16 + ki * 2 + (lane >> 3)) * 8 + (lane & 7)) * 4;

  // prefetch step-0 token + embedding quad
  int tok_n = x[em * Sz];
  float4 xv_n = *(const float4*)&W_xh[(size_t)tok_n * Hz + kcol];

  int rp = 0;                               // read generation = s % 3
  for (int s = 0; s < Sz; ++s) {
    const int wp = (rp == 2) ? 0 : rp + 1;  // write generation
    const unsigned tgt = (unsigned)(s + 1); // producers' step-s data flag

    // fine-grained parallel WAIT on 16 producer WAVES (R15-proven form)
    {
      const int bound = (s == 0) ? 131072 : 16384;
      for (int it = 0; it < bound; ++it) {
        unsigned v = 0xFFFFFFFFu;
        if (lane < 16)
          v = __hip_atomic_load(&flags[pflag], __ATOMIC_RELAXED,
                                __HIP_MEMORY_SCOPE_AGENT);
        if (__all(v >= tgt)) break;
        __builtin_amdgcn_s_sleep(1);
      }
      asm volatile("" ::: "memory");
    }

    // issue all 8 A-fragment loads (no drain, R15-verbatim), consume with
    // descending vmcnt gates; each A-plane feeds both n-tiles' MFMAs.
    u32x4 t[8];
    load8_nodrain(&g_hfrag[rp][bh][ki * 8][lane][0], t);
    f32x16 acc0 = {}, acc1 = {};

#define STAGE(P, CNT)                                                          \
    {                                                                          \
      asm volatile("s_waitcnt vmcnt(" #CNT ")" : "+v"(t[(P)]));                \
      acc0 = __builtin_amdgcn_mfma_f32_32x32x16_bf16(*(short8*)&t[(P)],        \
                                                     wf[0][(P)], acc0, 0, 0, 0);\
      acc1 = __builtin_amdgcn_mfma_f32_32x32x16_bf16(*(short8*)&t[(P)],        \
                                                     wf[1][(P)], acc1, 0, 0, 0);\
    }
    STAGE(0, 7) STAGE(1, 6) STAGE(2, 5) STAGE(3, 4)
    STAGE(4, 3) STAGE(5, 2) STAGE(6, 1) STAGE(7, 0)
#undef STAGE

    // prefetch NEXT step's token + embedding quad (hides gather latency)
    float4 xv = xv_n;
    if (s + 1 < Sz) {
      int t2 = x[em * Sz + s + 1];
      xv_n = *(const float4*)&W_xh[(size_t)t2 * Hz + kcol];
    }

    __syncthreads();   // BAR-A: prev step's epilogue done reading red
    // C/D: col=lane&31, row=(reg&3)+8*(reg>>2)+4*(lane>>5)  [m74/m101]
    // write both n-tiles; XOR swizzle keeps <=2 lanes/bank
    {
#pragma unroll
      for (int r = 0; r < 16; ++r) {
        int m = 4 * (lane >> 5) + (r & 3) + 8 * (r >> 2);
        int cA = (lane & 31);            // tile 0 col
        int cB = 32 + (lane & 31);       // tile 1 col
        red[ki * 2048 + m * 64 + (cA ^ m)] = acc0[r];
        red[ki * 2048 + m * 64 + (cB ^ m)] = acc1[r];
      }
    }
    __syncthreads();   // BAR-B: all 8 partials in red

    // epilogue: z = sum of 8 partials + emb + bias; h = tanh(z)
    float z[4];
#pragma unroll
    for (int j = 0; j < 4; ++j) {
      const int off = er * 64 + ((c0 + j) ^ er);
      z[j] = ((red[off] + red[2048 + off]) + (red[4096 + off] + red[6144 + off])) +
             ((red[8192 + off] + red[10240 + off]) +
              (red[12288 + off] + red[14336 + off]));
    }
    z[0] = fast_tanh(z[0] + xv.x + bias.x);
    z[1] = fast_tanh(z[1] + xv.y + bias.y);
    z[2] = fast_tanh(z[2] + xv.z + bias.z);
    z[3] = fast_tanh(z[3] + xv.w + bias.w);

    u32x2 w2;
    w2.x = (unsigned)f2bf(z[0]) | ((unsigned)f2bf(z[1]) << 16);
    w2.y = (unsigned)f2bf(z[2]) | ((unsigned)f2bf(z[3]) << 16);

    // h store -> per-wave drain -> per-wave flag publish (R15-proven)
    store8_sc1(&((unsigned short*)g_hfrag)[(size_t)wp * 65536 + slotOff], w2);
    asm volatile("s_waitcnt vmcnt(0)" ::: "memory");   // own stores visible
    if (lane == 0)
      __hip_atomic_store(&flags[(g * 8 + ki) * 4], (unsigned)(s + 2),
                         __ATOMIC_RELAXED, __HIP_MEMORY_SCOPE_AGENT);

    // off the publish path:
    *(u32x2*)&g_hidden[(size_t)s * 65536 + slotOff] = w2;
    if (s == Sz - 1) {
      float* hf = out + (size_t)Bz * Sz * Vz + (size_t)em * Hz + kcol;
      float4 f0 = {z[0], z[1], z[2], z[3]};
      *(float4*)hf = f0;
    }
    rp = wp;
  }
}

// ---------------- Phase 2: logits = hidden @ W_out + b_out -------------------
// grid: 1024 blocks = (s, mi); 4 waves; wave nt computes 32 rows x 32 cols, K=1024
__global__ __launch_bounds__(256) void logits_gemm(
    const float* __restrict__ b_out, float* __restrict__ out)
{
  const int tid = threadIdx.x, lane = tid & 63, nt = tid >> 6;
  const int s = blockIdx.x >> 1, mi = blockIdx.x & 1;
  const unsigned short* ab = &g_hidden[((size_t)s * 8192 + (size_t)mi * 4096) * 8];

  f32x16 acc = {};
#pragma unroll 8
  for (int kb = 0; kb < 64; ++kb) {
    short8 a = *(const short8*)&ab[(size_t)(kb * 64 + lane) * 8];
    short8 b = *(const short8*)&g_wout[(size_t)((kb * 4 + nt) * 64 + lane) * 8];
    acc = __builtin_amdgcn_mfma_f32_32x32x16_bf16(a, b, acc, 0, 0, 0);
  }
  const int col = nt * 32 + (lane & 31);
  const float bo = b_out[col];
  const int rbase = 4 * (lane >> 5);
#pragma unroll
  for (int r = 0; r < 16; ++r) {
    int m = rbase + (r & 3) + 8 * (r >> 2);
    int em = mi * 32 + m;
    out[((size_t)em * Sz + s) * Vz + col] = acc[r] + bo;
  }
}

// ---------------- host launcher ----------------------------------------------
extern "C" void kernel_launch(void* const* d_in, const int* in_sizes, int n_in,
                              void* d_out, int out_size, void* d_ws, size_t ws_size,
                              hipStream_t stream) {
  const int*   x     = (const int*)d_in[0];
  const float* h0    = (const float*)d_in[1];
  const float* W_xh  = (const float*)d_in[2];
  const float* W_hh  = (const float*)d_in[3];
  const float* b_h   = (const float*)d_in[4];
  const float* W_out = (const float*)d_in[5];
  const float* b_out = (const float*)d_in[6];
  float* out = (float*)d_out;

  (void)hipMemsetAsync(d_ws, 0, 8192, stream);    // 256 wave-flag slots (16 B)
  pack_wout<<<64, 256, 0, stream>>>(W_out);
  rnn_persistent<<<NWG, WGT, 0, stream>>>(x, h0, W_xh, W_hh, b_h, out,
                                          (unsigned*)d_ws);
  logits_gemm<<<Sz * 2, 256, 0, stream>>>(b_out, out);
}